// Round 7
// baseline (137.050 us; speedup 1.0000x reference)
//
#include <hip/hip_runtime.h>

typedef __attribute__((ext_vector_type(8))) short bf16x8;
typedef __attribute__((ext_vector_type(4))) float f32x4;

#define BTOT 32768
#define FDIM 128
#define TDIM 32
#define DDIM 16
#define HDIM 10
#define CDIM 320            // T*H
#define ALPHA_C 0.1f
#define MARGIN_C 1.0f
#define SLOPE_C 0.2f
#define OFFSET_C 1.0e6f

// ws float offsets
#define WS_A0BF 0           // 320*128 bf16 = 20480 floats of storage
#define WS_MEAN 20480       // 320 floats
#define WS_TC   20800       // 1 float (pad to 20864)
#define WS_CE   20864       // 32768 floats (direct-written per b)

// gemm0 LDS layout (bytes):
//  region1 @0:      xs[32][136] bf16 (8704 B)  -> dead after frag load -> mpart[32][81] f32 (10368 B)
//  region2 @10368:  a0s[80][136] bf16 (21760 B) -> after MFMA (accs in regs) -> ys[32][85] f32 (10880 B)
#define R2OFF 10368
#define LDS_TOTAL (R2OFF + 21760)   // 32128 B -> 5 blocks/CU by LDS
#define YSROW 85
#define MPROW 81

__device__ __forceinline__ float leaky(float x) { return x >= 0.f ? x : SLOPE_C * x; }

__device__ __forceinline__ unsigned short f2bf(float f) {   // RNE f32->bf16
    unsigned int u = __float_as_uint(f);
    u += 0x7fffu + ((u >> 16) & 1u);
    return (unsigned short)(u >> 16);
}

// A0bf[c][n] (bf16, c-major), c = t*10+o:  sum_d aw[t,n,d] * W0[o,d]
__global__ void prep_kernel(const float* __restrict__ aw, const float* __restrict__ W0,
                            unsigned short* __restrict__ a0bf) {
    int idx = blockIdx.x * blockDim.x + threadIdx.x;   // c*128 + n
    if (idx >= CDIM * FDIM) return;
    int c = idx >> 7, n = idx & 127;
    int t = c / HDIM, o = c - t * HDIM;
    const float* a = aw + ((size_t)t * FDIM + n) * DDIM;
    const float* w = W0 + o * DDIM;
    float s = 0.f;
#pragma unroll
    for (int d = 0; d < DDIM; ++d) s += a[d] * w[d];
    a0bf[idx] = f2bf(s);
}

// Fused layer0 GEMM + W1..W3 + head/CE + mean partials.
// Block: 256 thr = 4 waves; tile 32 b x 320 c, looping 4 c-chunks of 80.
// Waves: sub = w>>1 (16-row b-subtile), (w&1)==0 -> ct{0,1,2}, ==1 -> ct{3,4}.
__global__ __launch_bounds__(256, 5) void gemm0_fused(
    const float* __restrict__ X, const unsigned short* __restrict__ a0bf,
    const float* __restrict__ W1, const float* __restrict__ W2,
    const float* __restrict__ W3, const float* __restrict__ Wh,
    const float* __restrict__ bh,
    float* __restrict__ rep, float* __restrict__ ce_mean,
    float* __restrict__ mean_acc)
{
    __shared__ __align__(16) char ldsbuf[LDS_TOTAL];
    unsigned short (*xs)[136]  = (unsigned short (*)[136])ldsbuf;
    float* mpartf = (float*)ldsbuf;                         // after frag load
    unsigned short (*a0s)[136] = (unsigned short (*)[136])(ldsbuf + R2OFF);
    float* ysf = (float*)(ldsbuf + R2OFF);                  // after MFMA accs read a0s

    int tid = threadIdx.x;
    int b0 = blockIdx.x * 32;

    // ---- stage X tile once (32 rows x 128 cols), f32->bf16 via cvt_pk ----
#pragma unroll
    for (int k = 0; k < 4; ++k) {
        int idx = tid + k * 256;             // 1024 float4
        int row = idx >> 5, col4 = idx & 31;
        float4 v = reinterpret_cast<const float4*>(X + (size_t)(b0 + row) * FDIM)[col4];
        unsigned pk0, pk1;
        asm("v_cvt_pk_bf16_f32 %0, %1, %2" : "=v"(pk0) : "v"(v.x), "v"(v.y));
        asm("v_cvt_pk_bf16_f32 %0, %1, %2" : "=v"(pk1) : "v"(v.z), "v"(v.w));
        uint2 pk; pk.x = pk0; pk.y = pk1;
        *reinterpret_cast<uint2*>(&xs[row][col4 * 4]) = pk;
    }
    // ---- stage a0s for cc=0 ----
#pragma unroll
    for (int k = 0; k < 5; ++k) {
        int idx = tid + k * 256;             // 1280 uint4 = 80 rows x 16
        int row = idx >> 4, j = idx & 15;
        uint4 v = reinterpret_cast<const uint4*>(a0bf + (size_t)row * FDIM)[j];
        *reinterpret_cast<uint4*>(&a0s[row][j * 8]) = v;
    }
    __syncthreads();

    int lane = tid & 63, w = __builtin_amdgcn_readfirstlane(tid >> 6);
    int r16 = lane & 15, g = lane >> 4;
    int sub = w >> 1;
    int wodd = w & 1;
    // A-frags for this wave's 16-row subtile (xs dead afterwards)
    bf16x8 af[4];
#pragma unroll
    for (int s = 0; s < 4; ++s)
        af[s] = *reinterpret_cast<const bf16x8*>(&xs[sub * 16 + r16][s * 32 + g * 8]);

    int t8 = tid & 7, bl = tid >> 3;
    float ce_sum = 0.f;

    for (int cc = 0; cc < 4; ++cc) {
        // ---- MFMA: accs in registers (a0s still live) ----
        f32x4 acc0 = {0.f,0.f,0.f,0.f}, acc1 = {0.f,0.f,0.f,0.f}, acc2 = {0.f,0.f,0.f,0.f};
        if (wodd == 0) {
#pragma unroll
            for (int s = 0; s < 4; ++s) {
                bf16x8 bf0 = *reinterpret_cast<const bf16x8*>(&a0s[ 0 + r16][s * 32 + g * 8]);
                bf16x8 bf1 = *reinterpret_cast<const bf16x8*>(&a0s[16 + r16][s * 32 + g * 8]);
                bf16x8 bf2 = *reinterpret_cast<const bf16x8*>(&a0s[32 + r16][s * 32 + g * 8]);
                acc0 = __builtin_amdgcn_mfma_f32_16x16x32_bf16(af[s], bf0, acc0, 0, 0, 0);
                acc1 = __builtin_amdgcn_mfma_f32_16x16x32_bf16(af[s], bf1, acc1, 0, 0, 0);
                acc2 = __builtin_amdgcn_mfma_f32_16x16x32_bf16(af[s], bf2, acc2, 0, 0, 0);
            }
        } else {
#pragma unroll
            for (int s = 0; s < 4; ++s) {
                bf16x8 bf3 = *reinterpret_cast<const bf16x8*>(&a0s[48 + r16][s * 32 + g * 8]);
                bf16x8 bf4 = *reinterpret_cast<const bf16x8*>(&a0s[64 + r16][s * 32 + g * 8]);
                acc0 = __builtin_amdgcn_mfma_f32_16x16x32_bf16(af[s], bf3, acc0, 0, 0, 0);
                acc1 = __builtin_amdgcn_mfma_f32_16x16x32_bf16(af[s], bf4, acc1, 0, 0, 0);
            }
        }
        __syncthreads();   // (A) all a0s reads done -> ys may overwrite region2

        // ---- write D to ys: row = sub*16+g*4+r, col = ct*16+r16 ----
        int ybase = (sub * 16 + g * 4) * YSROW + r16;
        if (wodd == 0) {
#pragma unroll
            for (int r = 0; r < 4; ++r) {
                ysf[ybase + r * YSROW +  0] = acc0[r];
                ysf[ybase + r * YSROW + 16] = acc1[r];
                ysf[ybase + r * YSROW + 32] = acc2[r];
            }
        } else {
#pragma unroll
            for (int r = 0; r < 4; ++r) {
                ysf[ybase + r * YSROW + 48] = acc0[r];
                ysf[ybase + r * YSROW + 64] = acc1[r];
            }
        }
        __syncthreads();   // (B) ys complete

        // ---- epilogue: 1 (b,t) pair per thread ----
        int t = cc * 8 + t8;
        float* yrow = ysf + bl * YSROW + t8 * HDIM;
        float h[HDIM], lh[HDIM], gg[HDIM];
#pragma unroll
        for (int q = 0; q < HDIM; ++q) h[q] = yrow[q];
#pragma unroll
        for (int o = 0; o < HDIM; ++o) lh[o] = leaky(h[o]);
#pragma unroll
        for (int o = 0; o < HDIM; ++o) { float s = 0.f;
#pragma unroll
            for (int i = 0; i < HDIM; ++i) s += W1[o * HDIM + i] * lh[i]; gg[o] = s; }
#pragma unroll
        for (int o = 0; o < HDIM; ++o) lh[o] = leaky(gg[o]);
#pragma unroll
        for (int o = 0; o < HDIM; ++o) { float s = 0.f;
#pragma unroll
            for (int i = 0; i < HDIM; ++i) s += W2[o * HDIM + i] * lh[i]; h[o] = s; }
#pragma unroll
        for (int o = 0; o < HDIM; ++o) lh[o] = leaky(h[o]);
#pragma unroll
        for (int o = 0; o < HDIM; ++o) { float s = 0.f;
#pragma unroll
            for (int i = 0; i < HDIM; ++i) s += W3[o * HDIM + i] * lh[i]; gg[o] = s; }

        // rep back into own ys slot; mean partial into mpart (region1, xs dead)
#pragma unroll
        for (int q = 0; q < HDIM; ++q) yrow[q] = gg[q];
#pragma unroll
        for (int o = 0; o < HDIM; ++o) mpartf[bl * MPROW + t8 * HDIM + o] = gg[o];

        // head + CE(class=t), online logsumexp
#pragma unroll
        for (int o = 0; o < HDIM; ++o) lh[o] = leaky(gg[o]);
        float m = -1e30f, se = 0.f, pt = 0.f;
#pragma unroll
        for (int o = 0; o < TDIM; ++o) {
            float s = bh[o];
#pragma unroll
            for (int i = 0; i < HDIM; ++i) s += Wh[o * HDIM + i] * lh[i];
            pt = (o == t) ? s : pt;
            float nm = fmaxf(m, s);
            se = se * __expf(m - nm) + __expf(s - nm);
            m = nm;
        }
        ce_sum += m + __logf(se) - pt;
        __syncthreads();   // (C) ys rep-values + mpart complete

        // ---- copyout ys -> rep (b32, coalesced) ----
#pragma unroll
        for (int k = 0; k < 10; ++k) {
            int idx = tid + k * 256;         // 2560 words = 32 rows x 80
            int row = idx / 80, col = idx - row * 80;
            rep[(size_t)(b0 + row) * CDIM + cc * 80 + col] = ysf[row * YSROW + col];
        }
        // ---- mean reduce: 80 cols x 32 rows -> 1 atomic per col ----
        if (tid < 80) {
            float s = 0.f;
#pragma unroll
            for (int r = 0; r < 32; ++r) s += mpartf[r * MPROW + tid];
            atomicAdd(&mean_acc[cc * 80 + tid], s);
        }
        if (cc < 3) {
            __syncthreads();   // (D) ys/mpart reads done -> restage a0s
#pragma unroll
            for (int k = 0; k < 5; ++k) {
                int idx = tid + k * 256;
                int row = idx >> 4, j = idx & 15;
                uint4 v = reinterpret_cast<const uint4*>(
                    a0bf + (size_t)((cc + 1) * 80 + row) * FDIM)[j];
                *reinterpret_cast<uint4*>(&a0s[row][j * 8]) = v;
            }
            __syncthreads();   // (E) a0s ready
        }
    }

    // CE: sum over t8 lanes (xor 1,2,4 stays within the 8-lane group), direct store
    ce_sum += __shfl_xor(ce_sum, 1, 64);
    ce_sum += __shfl_xor(ce_sum, 2, 64);
    ce_sum += __shfl_xor(ce_sum, 4, 64);
    if (t8 == 0) ce_mean[b0 + bl] = ce_sum * (1.f / TDIM);
}

// Triplet-center hinge: block = 32 b's staged in LDS, thread = (t, 4 b's).
__global__ __launch_bounds__(256) void tc_kernel(const float* __restrict__ rep,
    const float* __restrict__ mean_acc, float* __restrict__ tc_sum)
{
    __shared__ float tile[32][CDIM];     // 40 KB
    __shared__ float mm[CDIM];
    __shared__ float msq[TDIM];
    __shared__ float wpart[4];
    int tid = threadIdx.x;
    int b0 = blockIdx.x * 32;

    for (int i = tid; i < CDIM; i += 256) mm[i] = mean_acc[i] * (1.f / BTOT);
    const float4* src = reinterpret_cast<const float4*>(rep + (size_t)b0 * CDIM);
#pragma unroll
    for (int k = 0; k < 10; ++k) {       // 2560 float4, coalesced
        int idx = tid + k * 256;
        int row = idx / 80, col4 = idx - row * 80;
        *reinterpret_cast<float4*>(&tile[row][col4 * 4]) = src[idx];
    }
    __syncthreads();
    if (tid < TDIM) {
        float s = 0.f;
#pragma unroll
        for (int h = 0; h < HDIM; ++h) { float v = mm[tid * HDIM + h]; s += v * v; }
        msq[tid] = s;
    }
    __syncthreads();

    int t = tid & 31, bg = tid >> 5;     // 8 b-groups x 4 b's
    float rv[4][HDIM], rsq[4];
#pragma unroll
    for (int j = 0; j < 4; ++j) {
        const float* rp = &tile[bg * 4 + j][t * HDIM];
        float s = 0.f;
#pragma unroll
        for (int q = 0; q < 5; ++q) {
            float2 v = reinterpret_cast<const float2*>(rp)[q];
            rv[j][2 * q] = v.x; rv[j][2 * q + 1] = v.y;
            s += v.x * v.x + v.y * v.y;
        }
        rsq[j] = s;
    }
    float pos[4], neg[4];
#pragma unroll
    for (int j = 0; j < 4; ++j) { pos[j] = 0.f; neg[j] = 1e30f; }
#pragma unroll 4
    for (int c = 0; c < TDIM; ++c) {
        float m0[HDIM];
#pragma unroll
        for (int q = 0; q < 5; ++q) {
            float2 v = reinterpret_cast<const float2*>(&mm[c * HDIM])[q];
            m0[2 * q] = v.x; m0[2 * q + 1] = v.y;
        }
        float mq = msq[c];
        bool isT = (c == t);
#pragma unroll
        for (int j = 0; j < 4; ++j) {
            float dot = 0.f;
#pragma unroll
            for (int h = 0; h < HDIM; ++h) dot += rv[j][h] * m0[h];
            float s = rsq[j] - 2.f * dot + mq;
            if (isT) pos[j] = s;
            float s2 = isT ? s + OFFSET_C : s;
            neg[j] = fminf(neg[j], s2);
        }
    }
    float hs = 0.f;
#pragma unroll
    for (int j = 0; j < 4; ++j) hs += fmaxf(pos[j] + MARGIN_C - neg[j], 0.f);
#pragma unroll
    for (int m = 1; m < 64; m <<= 1) hs += __shfl_xor(hs, m, 64);
    int lane = tid & 63, w = tid >> 6;
    if (lane == 0) wpart[w] = hs;
    __syncthreads();
    if (tid == 0) atomicAdd(tc_sum, wpart[0] + wpart[1] + wpart[2] + wpart[3]);
}

__global__ void final_kernel(const float* __restrict__ ce_mean,
                             const float* __restrict__ tc_sum, float* __restrict__ loss)
{
    int b = blockIdx.x * blockDim.x + threadIdx.x;
    if (b < BTOT)
        loss[b] = ALPHA_C * (tc_sum[0] * (1.f / ((float)BTOT * TDIM))) + ce_mean[b];
}

extern "C" void kernel_launch(void* const* d_in, const int* in_sizes, int n_in,
                              void* d_out, int out_size, void* d_ws, size_t ws_size,
                              hipStream_t stream) {
    const float* X  = (const float*)d_in[0];
    const float* aw = (const float*)d_in[1];
    const float* W0 = (const float*)d_in[2];
    const float* W1 = (const float*)d_in[3];
    const float* W2 = (const float*)d_in[4];
    const float* W3 = (const float*)d_in[5];
    const float* Wh = (const float*)d_in[6];
    const float* bh = (const float*)d_in[7];
    float* ws = (float*)d_ws;
    unsigned short* a0bf = (unsigned short*)(ws + WS_A0BF);
    float* mean_acc = ws + WS_MEAN;
    float* tc_sum   = ws + WS_TC;
    float* ce_mean  = ws + WS_CE;
    float* out_rep = (float*)d_out;        // [32768][320]
    float* loss = out_rep + (size_t)BTOT * TDIM * HDIM;

    hipMemsetAsync(mean_acc, 0, 384 * sizeof(float), stream);
    prep_kernel<<<(CDIM * FDIM) / 256, 256, 0, stream>>>(aw, W0, a0bf);
    gemm0_fused<<<BTOT / 32, 256, 0, stream>>>(X, a0bf, W1, W2, W3, Wh, bh,
                                               out_rep, ce_mean, mean_acc);
    tc_kernel<<<BTOT / 32, 256, 0, stream>>>(out_rep, mean_acc, tc_sum);
    final_kernel<<<BTOT / 256, 256, 0, stream>>>(ce_mean, tc_sum, loss);
}

// Round 8
// 90.827 us; speedup vs baseline: 1.5089x; 1.5089x over previous
//
#include <hip/hip_runtime.h>

typedef __attribute__((ext_vector_type(8))) short bf16x8;
typedef __attribute__((ext_vector_type(4))) float f32x4;

#define BTOT 32768
#define FDIM 128
#define TDIM 32
#define DDIM 16
#define HDIM 10
#define CDIM 320            // T*H
#define ALPHA_C 0.1f
#define MARGIN_C 1.0f
#define SLOPE_C 0.2f
#define OFFSET_C 1.0e6f

// ws float offsets
#define WS_A0BF 0           // 320*128 bf16 = 20480 floats of storage
#define WS_MEAN 20480       // 320 floats
#define WS_TC   20800       // 1 float (pad to 20864)
#define WS_CE   20864       // 32768 floats (atomic-accumulated)

// LDS overlay:
//  region1 @0:     xs[64][136] bf16 (17408 B) -> after frag load: ys[64][92] f32 (23552 B)
//  region2 @23552: a0s[80][136] bf16 (21760 B) -> after MFMA:    mpart[32][81] f32 (10368 B)
#define R2OFF 23552
#define LDS_TOTAL (R2OFF + 21760)   // 45312 B -> 3 blocks/CU
#define YSROW 92                    // 92%32=28; g*4*92 % 32 = 16 -> 2-way D-writes
#define MPROW 81                    // odd -> mixed-parity banks

__device__ __forceinline__ float leaky(float x) { return fmaxf(x, SLOPE_C * x); }

__device__ __forceinline__ unsigned short f2bf(float f) {   // RNE f32->bf16
    unsigned int u = __float_as_uint(f);
    u += 0x7fffu + ((u >> 16) & 1u);
    return (unsigned short)(u >> 16);
}

// A0bf[c][n] (bf16, c-major), c = t*10+o:  sum_d aw[t,n,d] * W0[o,d]
__global__ void prep_kernel(const float* __restrict__ aw, const float* __restrict__ W0,
                            unsigned short* __restrict__ a0bf) {
    int idx = blockIdx.x * blockDim.x + threadIdx.x;   // c*128 + n
    if (idx >= CDIM * FDIM) return;
    int c = idx >> 7, n = idx & 127;
    int t = c / HDIM, o = c - t * HDIM;
    const float* a = aw + ((size_t)t * FDIM + n) * DDIM;
    const float* w = W0 + o * DDIM;
    float s = 0.f;
#pragma unroll
    for (int d = 0; d < DDIM; ++d) s += a[d] * w[d];
    a0bf[idx] = f2bf(s);
}

// Fused layer0 GEMM (bf16 MFMA) + W1..W3 + head/CE + mean partials.
// Grid 2048 = 512 bchunk x 4 cchunk; block 256 thr = 4 waves; tile 64 b x 80 c.
__global__ __launch_bounds__(256, 3) void gemm0_fused(
    const float* __restrict__ X, const unsigned short* __restrict__ a0bf,
    const float* __restrict__ W1, const float* __restrict__ W2,
    const float* __restrict__ W3, const float* __restrict__ Wh,
    const float* __restrict__ bh,
    float* __restrict__ rep, float* __restrict__ ce_acc,
    float* __restrict__ mean_acc)
{
    __shared__ __align__(16) char ldsbuf[LDS_TOTAL];
    unsigned short (*xs)[136]  = (unsigned short (*)[136])ldsbuf;            // region1
    float* ysf = (float*)ldsbuf;                                             // region1 (after frags)
    unsigned short (*a0s)[136] = (unsigned short (*)[136])(ldsbuf + R2OFF);  // region2
    float* mpartf = (float*)(ldsbuf + R2OFF);                                // region2 (after MFMA)

    int tid = threadIdx.x;
    int bchunk = blockIdx.x >> 2, cchunk = blockIdx.x & 3;
    int b0 = bchunk * 64, c0 = cchunk * 80;

    // ---- stage X tile (64x128, f32->bf16 via cvt_pk), coalesced float4 ----
#pragma unroll
    for (int k = 0; k < 8; ++k) {
        int idx = tid + k * 256;             // 2048 float4
        int row = idx >> 5, col4 = idx & 31;
        float4 v = reinterpret_cast<const float4*>(X + (size_t)(b0 + row) * FDIM)[col4];
        unsigned pk0, pk1;
        asm("v_cvt_pk_bf16_f32 %0, %1, %2" : "=v"(pk0) : "v"(v.x), "v"(v.y));
        asm("v_cvt_pk_bf16_f32 %0, %1, %2" : "=v"(pk1) : "v"(v.z), "v"(v.w));
        uint2 pk; pk.x = pk0; pk.y = pk1;
        *reinterpret_cast<uint2*>(&xs[row][col4 * 4]) = pk;
    }
    // ---- stage A0 tile (80 rows x 256 B), coalesced uint4 ----
#pragma unroll
    for (int k = 0; k < 5; ++k) {
        int idx = tid + k * 256;             // 1280 uint4
        int row = idx >> 4, j = idx & 15;
        uint4 v = reinterpret_cast<const uint4*>(a0bf + (size_t)(c0 + row) * FDIM)[j];
        *reinterpret_cast<uint4*>(&a0s[row][j * 8]) = v;
    }
    __syncthreads();                                       // (1) tiles staged

    int lane = tid & 63, w = __builtin_amdgcn_readfirstlane(tid >> 6);
    int r16 = lane & 15, g = lane >> 4;
    // A-frags: lane holds X[w*16 + r16, k], k = s*32 + g*8 + [0..8)
    bf16x8 af[4];
#pragma unroll
    for (int s = 0; s < 4; ++s)
        af[s] = *reinterpret_cast<const bf16x8*>(&xs[w * 16 + r16][s * 32 + g * 8]);
    __syncthreads();                                       // (2) xs dead -> ys live

#pragma unroll
    for (int ct = 0; ct < 5; ++ct) {
        f32x4 acc = {0.f, 0.f, 0.f, 0.f};
#pragma unroll
        for (int s = 0; s < 4; ++s) {
            bf16x8 bfrag = *reinterpret_cast<const bf16x8*>(&a0s[ct * 16 + r16][s * 32 + g * 8]);
            acc = __builtin_amdgcn_mfma_f32_16x16x32_bf16(af[s], bfrag, acc, 0, 0, 0);
        }
        // D layout: row = g*4+r, col = ct*16+r16; ys col padded c+c/10 (== t8*11+o)
        int c = ct * 16 + r16;
        int cpad = c + c / 10;
        int ybase = (w * 16 + g * 4) * YSROW + cpad;
#pragma unroll
        for (int r = 0; r < 4; ++r) ysf[ybase + r * YSROW] = acc[r];
    }
    __syncthreads();                                       // (3) ys ready; a0s dead -> mpart live

    // ---- epilogue: 2 (b,t) pairs per thread ----
    int t8 = tid & 7, bl0 = tid >> 3;
    int t = cchunk * 8 + t8;
    float mgg[HDIM];
#pragma unroll
    for (int o = 0; o < HDIM; ++o) mgg[o] = 0.f;

#pragma unroll
    for (int p = 0; p < 2; ++p) {
        int bl = bl0 + p * 32;
        const float* yrow = ysf + bl * YSROW + t8 * 11;    // odd slot stride: banks spread
        float h[HDIM], lh[HDIM], gg[HDIM];
#pragma unroll
        for (int q = 0; q < HDIM; ++q) h[q] = yrow[q];
#pragma unroll
        for (int o = 0; o < HDIM; ++o) lh[o] = leaky(h[o]);
#pragma unroll
        for (int o = 0; o < HDIM; ++o) { float s = 0.f;
#pragma unroll
            for (int i = 0; i < HDIM; ++i) s += W1[o * HDIM + i] * lh[i]; gg[o] = s; }
#pragma unroll
        for (int o = 0; o < HDIM; ++o) lh[o] = leaky(gg[o]);
#pragma unroll
        for (int o = 0; o < HDIM; ++o) { float s = 0.f;
#pragma unroll
            for (int i = 0; i < HDIM; ++i) s += W2[o * HDIM + i] * lh[i]; h[o] = s; }
#pragma unroll
        for (int o = 0; o < HDIM; ++o) lh[o] = leaky(h[o]);
#pragma unroll
        for (int o = 0; o < HDIM; ++o) { float s = 0.f;
#pragma unroll
            for (int i = 0; i < HDIM; ++i) s += W3[o * HDIM + i] * lh[i]; gg[o] = s; }

        // direct rep store: 8 t8-lanes give 320 B contiguous per bl
        float* rp = rep + (size_t)(b0 + bl) * CDIM + c0 + t8 * 10;
#pragma unroll
        for (int q = 0; q < 5; ++q) {
            float2 v; v.x = gg[2 * q]; v.y = gg[2 * q + 1];
            reinterpret_cast<float2*>(rp)[q] = v;
        }
#pragma unroll
        for (int o = 0; o < HDIM; ++o) mgg[o] += gg[o];

        // head + CE(class=t): branchless single-exp online LSE
#pragma unroll
        for (int o = 0; o < HDIM; ++o) lh[o] = leaky(gg[o]);
        float m = -1e30f, se = 0.f, pt = 0.f;
#pragma unroll
        for (int o = 0; o < TDIM; ++o) {
            float s = bh[o];
#pragma unroll
            for (int i = 0; i < HDIM; ++i) s += Wh[o * HDIM + i] * lh[i];
            pt = (o == t) ? s : pt;
            float d = s - m;
            float e = __expf(-fabsf(d));
            float ra = d > 0.f ? e : 1.f;    // rescale factor for se
            float rb = d > 0.f ? 1.f : e;    // new term
            se = se * ra + rb;
            m = fmaxf(m, s);
        }
        float ce = m + __logf(se) - pt;
        ce += __shfl_xor(ce, 1, 64);
        ce += __shfl_xor(ce, 2, 64);
        ce += __shfl_xor(ce, 4, 64);
        if (t8 == 0) atomicAdd(&ce_acc[b0 + bl], ce);
    }

    // mean partials (over both pairs) -> mpart, then column reduce + atomic
#pragma unroll
    for (int o = 0; o < HDIM; ++o) mpartf[bl0 * MPROW + t8 * HDIM + o] = mgg[o];
    __syncthreads();                                       // (4) mpart ready
    if (tid < 80) {
        float s = 0.f;
#pragma unroll
        for (int r = 0; r < 32; ++r) s += mpartf[r * MPROW + tid];
        atomicAdd(&mean_acc[c0 + tid], s);
    }
}

// Triplet-center hinge: block = 32 b's staged in LDS, thread = (t, 4 b's).
__global__ __launch_bounds__(256) void tc_kernel(const float* __restrict__ rep,
    const float* __restrict__ mean_acc, float* __restrict__ tc_sum)
{
    __shared__ float tile[32][CDIM];     // 40 KB
    __shared__ float mm[CDIM];
    __shared__ float msq[TDIM];
    __shared__ float wpart[4];
    int tid = threadIdx.x;
    int b0 = blockIdx.x * 32;

    for (int i = tid; i < CDIM; i += 256) mm[i] = mean_acc[i] * (1.f / BTOT);
    const float4* src = reinterpret_cast<const float4*>(rep + (size_t)b0 * CDIM);
#pragma unroll
    for (int k = 0; k < 10; ++k) {       // 2560 float4, coalesced
        int idx = tid + k * 256;
        int row = idx / 80, col4 = idx - row * 80;
        *reinterpret_cast<float4*>(&tile[row][col4 * 4]) = src[idx];
    }
    __syncthreads();
    if (tid < TDIM) {
        float s = 0.f;
#pragma unroll
        for (int h = 0; h < HDIM; ++h) { float v = mm[tid * HDIM + h]; s += v * v; }
        msq[tid] = s;
    }
    __syncthreads();

    int t = tid & 31, bg = tid >> 5;     // 8 b-groups x 4 b's
    float rv[4][HDIM], rsq[4];
#pragma unroll
    for (int j = 0; j < 4; ++j) {
        const float* rp = &tile[bg * 4 + j][t * HDIM];
        float s = 0.f;
#pragma unroll
        for (int q = 0; q < 5; ++q) {
            float2 v = reinterpret_cast<const float2*>(rp)[q];
            rv[j][2 * q] = v.x; rv[j][2 * q + 1] = v.y;
            s += v.x * v.x + v.y * v.y;
        }
        rsq[j] = s;
    }
    float pos[4], neg[4];
#pragma unroll
    for (int j = 0; j < 4; ++j) { pos[j] = 0.f; neg[j] = 1e30f; }
#pragma unroll 4
    for (int c = 0; c < TDIM; ++c) {
        float m0[HDIM];
#pragma unroll
        for (int q = 0; q < 5; ++q) {
            float2 v = reinterpret_cast<const float2*>(&mm[c * HDIM])[q];
            m0[2 * q] = v.x; m0[2 * q + 1] = v.y;
        }
        float mq = msq[c];
        bool isT = (c == t);
#pragma unroll
        for (int j = 0; j < 4; ++j) {
            float dot = 0.f;
#pragma unroll
            for (int h = 0; h < HDIM; ++h) dot += rv[j][h] * m0[h];
            float s = rsq[j] - 2.f * dot + mq;
            if (isT) pos[j] = s;
            float s2 = isT ? s + OFFSET_C : s;
            neg[j] = fminf(neg[j], s2);
        }
    }
    float hs = 0.f;
#pragma unroll
    for (int j = 0; j < 4; ++j) hs += fmaxf(pos[j] + MARGIN_C - neg[j], 0.f);
#pragma unroll
    for (int m = 1; m < 64; m <<= 1) hs += __shfl_xor(hs, m, 64);
    int lane = tid & 63, w = tid >> 6;
    if (lane == 0) wpart[w] = hs;
    __syncthreads();
    if (tid == 0) atomicAdd(tc_sum, wpart[0] + wpart[1] + wpart[2] + wpart[3]);
}

__global__ void final_kernel(const float* __restrict__ ce_acc,
                             const float* __restrict__ tc_sum, float* __restrict__ loss)
{
    int b = blockIdx.x * blockDim.x + threadIdx.x;
    if (b < BTOT)
        loss[b] = ALPHA_C * (tc_sum[0] * (1.f / ((float)BTOT * TDIM)))
                + ce_acc[b] * (1.f / TDIM);
}

extern "C" void kernel_launch(void* const* d_in, const int* in_sizes, int n_in,
                              void* d_out, int out_size, void* d_ws, size_t ws_size,
                              hipStream_t stream) {
    const float* X  = (const float*)d_in[0];
    const float* aw = (const float*)d_in[1];
    const float* W0 = (const float*)d_in[2];
    const float* W1 = (const float*)d_in[3];
    const float* W2 = (const float*)d_in[4];
    const float* W3 = (const float*)d_in[5];
    const float* Wh = (const float*)d_in[6];
    const float* bh = (const float*)d_in[7];
    float* ws = (float*)d_ws;
    unsigned short* a0bf = (unsigned short*)(ws + WS_A0BF);
    float* mean_acc = ws + WS_MEAN;
    float* tc_sum   = ws + WS_TC;
    float* ce_acc   = ws + WS_CE;
    float* out_rep = (float*)d_out;        // [32768][320]
    float* loss = out_rep + (size_t)BTOT * TDIM * HDIM;

    // zero mean_acc + tc pad + ce_acc
    hipMemsetAsync(mean_acc, 0, (384 + BTOT) * sizeof(float), stream);
    prep_kernel<<<(CDIM * FDIM) / 256, 256, 0, stream>>>(aw, W0, a0bf);
    gemm0_fused<<<2048, 256, 0, stream>>>(X, a0bf, W1, W2, W3, Wh, bh,
                                          out_rep, ce_acc, mean_acc);
    tc_kernel<<<BTOT / 32, 256, 0, stream>>>(out_rep, mean_acc, tc_sum);
    final_kernel<<<BTOT / 256, 256, 0, stream>>>(ce_acc, tc_sum, loss);
}